// Round 9
// baseline (70.932 us; speedup 1.0000x reference)
//
#include <hip/hip_runtime.h>

#define GAMMA_C 0.2f

// pos = ALPHA     * ln2 * s2 * exp2(-g*a2)
// neg = (1-ALPHA) * ln2 * a2 * exp2(-g*s2)
// where s2 = log2(1 + exp2(-x*log2e)), a2 = x*log2e + s2.
#define L2E_C 1.4426950408889634f
#define CPOS_C 0.41588830833596715f  // 0.6 * ln2
#define CNEG_C 0.27725887222397810f  // 0.4 * ln2

// Fixed-point scale for the deterministic integer reduction.
// Per-block sum <= ~1.6e5; 1.6e5 * 2^30 * 1024 blocks ~= 1.8e17 << 2^63.
#define FP_SCALE 1073741824.0f       // 2^30
#define FP_INV_SCALE 9.31322574615478515625e-10  // 2^-30 (exact in double)

typedef float __attribute__((ext_vector_type(4))) f32x4;
typedef int   __attribute__((ext_vector_type(4))) i32x4;

__device__ __forceinline__ float focal_elem(float x, int t) {
    float xl = x * L2E_C;
    float e  = __builtin_amdgcn_exp2f(-xl);       // exp(-x)
    float s2 = __builtin_amdgcn_logf(1.0f + e);   // softplus(-x)/ln2
    float a2 = xl + s2;                           // (x + softplus(-x))/ln2
    bool ispos = (t == 1);
    float earg = ispos ? a2 : s2;
    float fac  = ispos ? s2 : a2;
    float cf   = ispos ? CPOS_C : CNEG_C;
    float ex   = __builtin_amdgcn_exp2f(-GAMMA_C * earg);
    return cf * fac * ex;
}

__device__ __forceinline__ float focal_vec4(f32x4 x4, i32x4 t4) {
    float r = focal_elem(x4.x, t4.x);
    r += focal_elem(x4.y, t4.y);
    r += focal_elem(x4.z, t4.z);
    r += focal_elem(x4.w, t4.w);
    return r;
}

// Single fused kernel: block-contiguous sweep (160 KB/stream/block), 8-deep
// unroll, then a fence-free deterministic device reduction:
//   - per-block sum -> fixed-point int64 -> ONE relaxed atomicAdd
//   - relaxed counter; last block re-reads sum via atomicAdd(ptr,0) and
//     writes the mean. Integer adds are order-independent -> deterministic.
// No agent-scope release/acquire (R4 showed those invalidate L2 per block).
__global__ __launch_bounds__(256) void focal_fused_kernel(
    const f32x4* __restrict__ logits4,
    const i32x4* __restrict__ target4,
    unsigned long long* __restrict__ fpsum,   // ws[0]
    unsigned* __restrict__ ctr,               // ws[8]
    long long nvec,
    const float* __restrict__ logits_s,   // scalar views for tail
    const int* __restrict__ target_s,
    long long n,
    float* __restrict__ out)
{
    const long long chunk = (nvec + gridDim.x - 1) / gridDim.x;
    const long long start = (long long)blockIdx.x * chunk;
    long long end_ll = start + chunk;
    if (end_ll > nvec) end_ll = nvec;
    const int len = (int)(end_ll > start ? end_ll - start : 0);

    const f32x4* __restrict__ lg = logits4 + start;
    const i32x4* __restrict__ tg = target4 + start;

    float a0 = 0.0f, a1 = 0.0f, a2 = 0.0f, a3 = 0.0f;

    int k = threadIdx.x;
    for (; k + 1792 < len; k += 2048) {
        f32x4 x0 = lg[k];
        f32x4 x1 = lg[k + 256];
        f32x4 x2 = lg[k + 512];
        f32x4 x3 = lg[k + 768];
        f32x4 x4 = lg[k + 1024];
        f32x4 x5 = lg[k + 1280];
        f32x4 x6 = lg[k + 1536];
        f32x4 x7 = lg[k + 1792];
        i32x4 t0 = tg[k];
        i32x4 t1 = tg[k + 256];
        i32x4 t2 = tg[k + 512];
        i32x4 t3 = tg[k + 768];
        i32x4 t4 = tg[k + 1024];
        i32x4 t5 = tg[k + 1280];
        i32x4 t6 = tg[k + 1536];
        i32x4 t7 = tg[k + 1792];
        a0 += focal_vec4(x0, t0);
        a1 += focal_vec4(x1, t1);
        a2 += focal_vec4(x2, t2);
        a3 += focal_vec4(x3, t3);
        a0 += focal_vec4(x4, t4);
        a1 += focal_vec4(x5, t5);
        a2 += focal_vec4(x6, t6);
        a3 += focal_vec4(x7, t7);
    }
    for (; k < len; k += 256)
        a0 += focal_vec4(lg[k], tg[k]);

    float acc = (a0 + a1) + (a2 + a3);

    // Tail (n % 4 != 0) — no-op for this problem shape.
    if (blockIdx.x == 0 && threadIdx.x == 0) {
        for (long long q = nvec * 4; q < n; ++q)
            acc += focal_elem(logits_s[q], target_s[q]);
    }

    // Wave (64-lane) reduction
#pragma unroll
    for (int off = 32; off > 0; off >>= 1)
        acc += __shfl_down(acc, off, 64);

    __shared__ float smem[4];
    __shared__ bool is_last;
    int lane = threadIdx.x & 63;
    int wid  = threadIdx.x >> 6;
    if (lane == 0) smem[wid] = acc;
    __syncthreads();

    if (threadIdx.x == 0) {
        float bsum = smem[0] + smem[1] + smem[2] + smem[3];
        // Loss is strictly positive -> q >= 0 fits unsigned.
        unsigned long long q =
            (unsigned long long)(long long)rintf(bsum * FP_SCALE);
        unsigned long long old = atomicAdd(fpsum, q);   // relaxed, no fence
        // Consume `old` so the add's completion (vmcnt) precedes the counter.
        asm volatile("" :: "v"(old));
        unsigned prev = atomicAdd(ctr, 1u);             // relaxed
        if (prev == gridDim.x - 1u) {
            // Same-address RMW -> serialized at the coherence point after
            // all 1024 adds (each add completed before its counter inc).
            unsigned long long total = atomicAdd(fpsum, 0ull);
            out[0] = (float)((double)total * FP_INV_SCALE / (double)n);
        }
    }
}

extern "C" void kernel_launch(void* const* d_in, const int* in_sizes, int n_in,
                              void* d_out, int out_size, void* d_ws, size_t ws_size,
                              hipStream_t stream) {
    const float* logits = (const float*)d_in[0];
    const int*   target = (const int*)d_in[1];
    long long n = (long long)in_sizes[0];     // N*C = 41,943,040
    long long nvec = n / 4;

    unsigned long long* fpsum = (unsigned long long*)d_ws;
    unsigned* ctr = (unsigned*)((char*)d_ws + 8);
    const int nblocks = 1024;                 // 4 blocks/CU, 160 KB/stream
    const int nthreads = 256;

    hipMemsetAsync(d_ws, 0, 16, stream);
    focal_fused_kernel<<<nblocks, nthreads, 0, stream>>>(
        (const f32x4*)logits, (const i32x4*)target, fpsum, ctr, nvec,
        logits, target, n, (float*)d_out);
}

// Round 10
// 60.235 us; speedup vs baseline: 1.1776x; 1.1776x over previous
//
#include <hip/hip_runtime.h>

#define GAMMA_C 0.2f

// pos = ALPHA     * ln2 * s2 * exp2(-g*a2)
// neg = (1-ALPHA) * ln2 * a2 * exp2(-g*s2)
// where s2 = log2(1 + exp2(-x*log2e)), a2 = x*log2e + s2.
#define L2E_C 1.4426950408889634f
#define CPOS_C 0.41588830833596715f  // 0.6 * ln2
#define CNEG_C 0.27725887222397810f  // 0.4 * ln2

typedef float __attribute__((ext_vector_type(4))) f32x4;
typedef int   __attribute__((ext_vector_type(4))) i32x4;

__device__ __forceinline__ float focal_elem(float x, int t) {
    float xl = x * L2E_C;
    float e  = __builtin_amdgcn_exp2f(-xl);       // exp(-x)
    float s2 = __builtin_amdgcn_logf(1.0f + e);   // softplus(-x)/ln2
    float a2 = xl + s2;                           // (x + softplus(-x))/ln2
    bool ispos = (t == 1);
    float earg = ispos ? a2 : s2;
    float fac  = ispos ? s2 : a2;
    float cf   = ispos ? CPOS_C : CNEG_C;
    float ex   = __builtin_amdgcn_exp2f(-GAMMA_C * earg);
    return cf * fac * ex;
}

__device__ __forceinline__ float focal_vec4(f32x4 x4, i32x4 t4) {
    float r = focal_elem(x4.x, t4.x);
    r += focal_elem(x4.y, t4.y);
    r += focal_elem(x4.z, t4.z);
    r += focal_elem(x4.w, t4.w);
    return r;
}

// Stage 1: block-contiguous partition, 1024 blocks (160 KB contiguous sweep
// per stream per block -> fewer, longer DRAM streams), 8-deep unroll
// (16 outstanding 16B loads/thread). For this shape: len=10240 vec4,
// exactly 5 unrolled iterations, no remainder.
__global__ __launch_bounds__(256) void focal_partial_kernel(
    const f32x4* __restrict__ logits4,
    const i32x4* __restrict__ target4,
    float* __restrict__ partial,
    long long nvec,
    const float* __restrict__ logits_s,   // scalar views for tail
    const int* __restrict__ target_s,
    long long n)
{
    const long long chunk = (nvec + gridDim.x - 1) / gridDim.x;
    const long long start = (long long)blockIdx.x * chunk;
    long long end_ll = start + chunk;
    if (end_ll > nvec) end_ll = nvec;
    const int len = (int)(end_ll > start ? end_ll - start : 0);

    const f32x4* __restrict__ lg = logits4 + start;
    const i32x4* __restrict__ tg = target4 + start;

    float a0 = 0.0f, a1 = 0.0f, a2 = 0.0f, a3 = 0.0f;

    int k = threadIdx.x;
    for (; k + 1792 < len; k += 2048) {
        f32x4 x0 = lg[k];
        f32x4 x1 = lg[k + 256];
        f32x4 x2 = lg[k + 512];
        f32x4 x3 = lg[k + 768];
        f32x4 x4 = lg[k + 1024];
        f32x4 x5 = lg[k + 1280];
        f32x4 x6 = lg[k + 1536];
        f32x4 x7 = lg[k + 1792];
        i32x4 t0 = tg[k];
        i32x4 t1 = tg[k + 256];
        i32x4 t2 = tg[k + 512];
        i32x4 t3 = tg[k + 768];
        i32x4 t4 = tg[k + 1024];
        i32x4 t5 = tg[k + 1280];
        i32x4 t6 = tg[k + 1536];
        i32x4 t7 = tg[k + 1792];
        a0 += focal_vec4(x0, t0);
        a1 += focal_vec4(x1, t1);
        a2 += focal_vec4(x2, t2);
        a3 += focal_vec4(x3, t3);
        a0 += focal_vec4(x4, t4);
        a1 += focal_vec4(x5, t5);
        a2 += focal_vec4(x6, t6);
        a3 += focal_vec4(x7, t7);
    }
    for (; k < len; k += 256)
        a0 += focal_vec4(lg[k], tg[k]);

    float acc = (a0 + a1) + (a2 + a3);

    // Tail (n % 4 != 0) — no-op for this problem shape.
    if (blockIdx.x == 0 && threadIdx.x == 0) {
        for (long long q = nvec * 4; q < n; ++q)
            acc += focal_elem(logits_s[q], target_s[q]);
    }

    // Wave (64-lane) reduction
#pragma unroll
    for (int off = 32; off > 0; off >>= 1)
        acc += __shfl_down(acc, off, 64);

    __shared__ float smem[4];
    int lane = threadIdx.x & 63;
    int wid  = threadIdx.x >> 6;
    if (lane == 0) smem[wid] = acc;
    __syncthreads();
    if (threadIdx.x == 0)
        partial[blockIdx.x] = smem[0] + smem[1] + smem[2] + smem[3];
}

// Stage 2: deterministic reduce of per-block partials, apply mean, write out.
__global__ __launch_bounds__(256) void focal_final_kernel(
    const float* __restrict__ partial,
    int nblocks,
    float inv_count,
    float* __restrict__ out)
{
    float acc = 0.0f;
    for (int i = threadIdx.x; i < nblocks; i += 256)
        acc += partial[i];

#pragma unroll
    for (int off = 32; off > 0; off >>= 1)
        acc += __shfl_down(acc, off, 64);

    __shared__ float smem[4];
    int lane = threadIdx.x & 63;
    int wid  = threadIdx.x >> 6;
    if (lane == 0) smem[wid] = acc;
    __syncthreads();
    if (threadIdx.x == 0)
        out[0] = (smem[0] + smem[1] + smem[2] + smem[3]) * inv_count;
}

extern "C" void kernel_launch(void* const* d_in, const int* in_sizes, int n_in,
                              void* d_out, int out_size, void* d_ws, size_t ws_size,
                              hipStream_t stream) {
    const float* logits = (const float*)d_in[0];
    const int*   target = (const int*)d_in[1];
    long long n = (long long)in_sizes[0];     // N*C = 41,943,040
    long long nvec = n / 4;

    float* partial = (float*)d_ws;
    const int nblocks = 1024;                 // 4 blocks/CU, 160 KB/stream
    const int nthreads = 256;

    focal_partial_kernel<<<nblocks, nthreads, 0, stream>>>(
        (const f32x4*)logits, (const i32x4*)target, partial, nvec,
        logits, target, n);
    focal_final_kernel<<<1, nthreads, 0, stream>>>(
        partial, nblocks, 1.0f / (float)n, (float*)d_out);
}